// Round 17
// baseline (508.915 us; speedup 1.0000x reference)
//
#include <hip/hip_runtime.h>
#include <math.h>

#define TT 512
#define BB 256
#define OBSZ 128
#define HH 64
#define G3 192
#define NROW (TT*BB)
#define SEGCAP 128

// ---- fast transcendentals: ONLY used downstream of sign() (MLP heads) -----
__device__ __forceinline__ float fast_rcp(float x) {
    return __builtin_amdgcn_rcpf(x);
}
__device__ __forceinline__ float tanh_fast(float x) {
    float xc = fminf(fmaxf(x, -20.0f), 20.0f);   // clamp: avoid inf/inf NaN
    float e2 = __expf(2.0f * xc);
    return (e2 - 1.0f) * fast_rcp(e2 + 1.0f);
}

// ---------------------------------------------------------------------------
// Segment table build + length-desc sort (r7/r8 verbatim).
// ---------------------------------------------------------------------------
__global__ __launch_bounds__(64, 1)
void seg_build_kernel(const float* __restrict__ done,
                      unsigned int* __restrict__ segs, int* __restrict__ segcnt)
{
    const int b = blockIdx.x;
    const int l = threadIdx.x;
    __shared__ int starts[SEGCAP];
    __shared__ int scnt_s;

    unsigned int m = 0;
    #pragma unroll
    for (int k = 0; k < 8; ++k) {
        int t = l*8 + k;
        float d = done[(size_t)t*BB + b];
        if (t > 0 && d != 0.f) m |= (1u << k);
    }
    int cnt = __popc(m) + (l == 0 ? 1 : 0);
    int inc = cnt;
    for (int s = 1; s < 64; s <<= 1) {
        int v = __shfl_up(inc, s);
        if (l >= s) inc += v;
    }
    int total = __shfl(inc, 63);
    int w = inc - cnt;
    if (l == 0 && w < SEGCAP) starts[w++] = 0;
    #pragma unroll
    for (int k = 0; k < 8; ++k)
        if (m & (1u << k)) { if (w < SEGCAP) starts[w] = l*8 + k; ++w; }
    if (l == 0) scnt_s = (total < SEGCAP) ? total : SEGCAP;
    __syncthreads();

    const int n = scnt_s;
    for (int i = l; i < n; i += 64) {
        int t0 = starts[i];
        int t1 = (i+1 < n) ? starts[i+1] : TT;
        int li = t1 - t0;
        int rank = 0;
        for (int j = 0; j < n; ++j) {
            int s0 = starts[j];
            int s1 = (j+1 < n) ? starts[j+1] : TT;
            int lj = s1 - s0;
            rank += (int)((lj > li) || (lj == li && j < i));
        }
        segs[(size_t)b*SEGCAP + rank] = (unsigned int)t0 | ((unsigned int)li << 16);
    }
    if (l == 0) segcnt[b] = n;
}

// ---------------------------------------------------------------------------
// Segment-parallel GRU scan v5 (proven 228us, r10-r16 -- structural floor:
// transpose null, w-shared quad -24%, occupancy pairing +5% kept).
// ---------------------------------------------------------------------------
__global__ __launch_bounds__(512, 6)
void seg_scan_kernel(const float* __restrict__ gi_ws, const float* __restrict__ h0,
                     const float* __restrict__ done,
                     const float* __restrict__ w_hh, const float* __restrict__ b_hh,
                     const unsigned int* __restrict__ segs, const int* __restrict__ segcnt,
                     signed char* __restrict__ hidden, float* __restrict__ state_out)
{
    const int b    = blockIdx.x;
    const int scnt = segcnt[b];
    const int si0  = blockIdx.y * 2;
    if (si0 >= scnt) return;                     // uniform: both pair slots empty

    __shared__ __align__(16) float ws[G3*68];    // 52.2 KB
    __shared__ __align__(16) float hb[2][HH];
    __shared__ __align__(16) float srz[2][2*HH];
    __shared__ __align__(16) float shnb[2][HH];  // total 54,272 B -> 3 blocks/CU

    const int tid = threadIdx.x;
    #pragma unroll
    for (int i = 0; i < 6; ++i) {                // stage w_hh [192][64] -> stride 68
        int idx = tid + i*512;                   // float4 chunk 0..3071
        int g = idx >> 4, k4 = idx & 15;
        *(float4*)&ws[g*68 + k4*4] = *(const float4*)&w_hh[g*HH + k4*4];
    }

    const int grp = tid >> 8;                    // segment group 0/1 (wave-aligned)
    const int tau = tid & 255;                   // thread index within group
    const int si  = si0 + grp;

    int t0 = 0, len = 0;
    if (si < scnt) {
        unsigned int sg = segs[(size_t)b*SEGCAP + si];
        t0  = (int)(sg & 0xffffu);
        len = (int)(sg >> 16);
    }
    // uniform loop bound: sorted order -> rank si0 is the longer of the pair
    const int lmax = (int)(segs[(size_t)b*SEGCAP + si0] >> 16);

    const size_t gbase = (size_t)b*TT;           // [b][t][G3] layout

    float bh = 0.f, gp0 = 0.f, gp1 = 0.f;        // dot threads (r,z,n rows)
    float gn0 = 0.f, gn1 = 0.f;                  // gate threads: own gi_n stream
    if (tau < G3) {
        bh  = b_hh[tau];
        gp0 = gi_ws[(gbase + t0)*G3 + tau];
        if (len > 1) gp1 = gi_ws[(gbase + t0+1)*G3 + tau];
    } else {
        const int hl = tau - G3;
        float hi = 0.f;
        if (len > 0 && t0 == 0) {
            float d0 = done[b];
            hi = (1.0f - d0) * h0[b*HH + hl];
        }
        hb[grp][hl] = hi;
        gn0 = gi_ws[(gbase + t0)*G3 + 128 + hl];
        if (len > 1) gn1 = gi_ws[(gbase + t0+1)*G3 + 128 + hl];
    }
    __syncthreads();

    for (int tt = 0; tt < lmax; ++tt) {
        const int t = t0 + tt;
        if (tau < G3 && tt < len) {
            float gi = gp0;
            gp0 = gp1;
            if (tt+2 < len) gp1 = gi_ws[(gbase + t+2)*G3 + tau];
            // h via one lane-spread b32 read + readlane (bit-copy -> exact)
            int hvi = __float_as_int(hb[grp][tau & 63]);
            const float* wrow = &ws[tau*68];
            float a0=0.f, a1=0.f, a2=0.f, a3=0.f;
            #pragma unroll
            for (int j4 = 0; j4 < HH/4; ++j4) {
                float4 wv = *(const float4*)(wrow + j4*4);
                a0 = fmaf(__int_as_float(__builtin_amdgcn_readlane(hvi, 4*j4+0)), wv.x, a0);
                a1 = fmaf(__int_as_float(__builtin_amdgcn_readlane(hvi, 4*j4+1)), wv.y, a1);
                a2 = fmaf(__int_as_float(__builtin_amdgcn_readlane(hvi, 4*j4+2)), wv.z, a2);
                a3 = fmaf(__int_as_float(__builtin_amdgcn_readlane(hvi, 4*j4+3)), wv.w, a3);
            }
            float gh = bh + ((a0+a1)+(a2+a3));
            if (tau < 2*HH) srz[grp][tau] = gi + gh;        // r,z pre-acts
            else            shnb[grp][tau-2*HH] = gh;       // n: gh only
        }
        __syncthreads();   // (A) srz/shnb ready; hb reads complete

        if (tau >= G3 && tt < len) {
            const int hl = tau - G3;
            float gin = gn0;
            gn0 = gn1;
            if (tt+2 < len) gn1 = gi_ws[(gbase + t+2)*G3 + 128 + hl];
            float sr = srz[grp][hl];
            float sz = srz[grp][HH + hl];
            float r = 1.0f / (1.0f + expf(-sr));   // libm: precision-critical
            float z = 1.0f / (1.0f + expf(-sz));
            float n = tanhf(gin + r * shnb[grp][hl]);
            float hm = hb[grp][hl];
            float hnew = (1.0f - z)*n + z*hm;
            float s = (hnew > 0.f) ? 1.f : ((hnew < 0.f) ? -1.f : 0.f);
            hidden[(size_t)(t*BB + b)*HH + hl] = (signed char)s;
            if (t == TT-1) state_out[b*HH + hl] = s;
            hb[grp][hl] = s;   // interior steps of a segment have done==0
        }
        __syncthreads();   // (B) hb ready for next step
    }
}

// ---------------------------------------------------------------------------
// gi projection v5: G-SPLIT for occupancy. gridDim.y=2 halves the gate rows
// per block (96 of 192) -> ws 26.1KB -> launch_bounds(256,4): 4 blocks/CU,
// 4 waves/SIMD (2x the TLP that left r16's version at 31% of its VALU floor).
// acc shrinks 96->48 regs -> live ~105 under the 128 budget (r11's 3-block
// attempt failed on a 170-budget/150-live squeeze; this has real margin).
// x rows are read by 2 blocks (L2/L3-cached, ~11us extra overlapped traffic).
// Chains per output: k mod 4 -> c0..c3, k ascending (half0 then half1),
// final b + ((c0+c1)+(c2+c3)) -> BIT-IDENTICAL to all passing rounds.
// Output permuted to [b][t][G3] (r14).
// ---------------------------------------------------------------------------
__global__ __launch_bounds__(256, 4)
void gi_proj_kernel(const float* __restrict__ x,
                    const float* __restrict__ w_ih, const float* __restrict__ b_ih,
                    float* __restrict__ gi_ws)
{
    __shared__ __align__(16) float ws[96*68];     // 26.1 KB
    const int tid  = threadIdx.x;
    const int q    = tid & 31;    // g-lane: owns g = gh*96 + q + 32*jj, jj=0..2
    const int rp   = tid >> 5;    // row-group 0..7: rows rp*4 .. rp*4+3
    const int rowb = blockIdx.x * 32;
    const int gh   = blockIdx.y;  // g-half: rows [gh*96, gh*96+96)
    const int gbase0 = gh * 96;

    float bg[3];
    #pragma unroll
    for (int jj = 0; jj < 3; ++jj) bg[jj] = b_ih[gbase0 + q + 32*jj];

    float c0[3][4], c1[3][4], c2[3][4], c3[3][4];
    #pragma unroll
    for (int jj = 0; jj < 3; ++jj)
        #pragma unroll
        for (int r = 0; r < 4; ++r) { c0[jj][r]=0.f; c1[jj][r]=0.f; c2[jj][r]=0.f; c3[jj][r]=0.f; }

    #pragma unroll
    for (int half = 0; half < 2; ++half) {
        __syncthreads();                         // prior-half readers done
        #pragma unroll
        for (int i = 0; i < 6; ++i) {            // stage w half [96][64] -> stride 68
            int idx = tid + i*256;               // 0..1535
            int g = idx >> 4, k4 = idx & 15;
            *(float4*)&ws[g*68 + k4*4] =
                *(const float4*)&w_ih[(size_t)(gbase0 + g)*OBSZ + half*64 + k4*4];
        }
        __syncthreads();

        for (int kc = 0; kc < 8; ++kc) {         // 8 k-floats per chunk
            float cv[4][8];
            #pragma unroll
            for (int r = 0; r < 4; ++r) {
                const float* xp = x + (size_t)(rowb + rp*4 + r)*OBSZ + half*64 + kc*8;
                float4 a = *(const float4*)xp;
                float4 c = *(const float4*)(xp + 4);
                cv[r][0]=a.x; cv[r][1]=a.y; cv[r][2]=a.z; cv[r][3]=a.w;
                cv[r][4]=c.x; cv[r][5]=c.y; cv[r][6]=c.z; cv[r][7]=c.w;
            }
            #pragma unroll
            for (int jj = 0; jj < 3; ++jj) {
                const float* wp = &ws[(q + 32*jj)*68 + kc*8];
                float4 w0 = *(const float4*)wp;
                float4 w1 = *(const float4*)(wp + 4);
                #pragma unroll
                for (int r = 0; r < 4; ++r) {
                    c0[jj][r] = fmaf(cv[r][0], w0.x, c0[jj][r]);
                    c1[jj][r] = fmaf(cv[r][1], w0.y, c1[jj][r]);
                    c2[jj][r] = fmaf(cv[r][2], w0.z, c2[jj][r]);
                    c3[jj][r] = fmaf(cv[r][3], w0.w, c3[jj][r]);
                    c0[jj][r] = fmaf(cv[r][4], w1.x, c0[jj][r]);
                    c1[jj][r] = fmaf(cv[r][5], w1.y, c1[jj][r]);
                    c2[jj][r] = fmaf(cv[r][6], w1.z, c2[jj][r]);
                    c3[jj][r] = fmaf(cv[r][7], w1.w, c3[jj][r]);
                }
            }
        }
    }

    #pragma unroll
    for (int r = 0; r < 4; ++r) {
        const int row = rowb + rp*4 + r;                 // = t*BB + b
        const size_t rowp = ((size_t)(row & (BB-1)) << 9) | (row >> 8);  // b*TT+t
        #pragma unroll
        for (int jj = 0; jj < 3; ++jj) {
            float o = bg[jj] + ((c0[jj][r]+c1[jj][r]) + (c2[jj][r]+c3[jj][r]));
            gi_ws[rowp*G3 + gbase0 + q + 32*jj] = o;
        }
    }
}

// ---------------------------------------------------------------------------
// Fallback fused scan (round-4 verbatim) for when ws_size is too small.
// ---------------------------------------------------------------------------
__global__ __launch_bounds__(256, 1)
void scan_kernel_fused(const float* __restrict__ x, const float* __restrict__ h0,
                       const float* __restrict__ done,
                       const float* __restrict__ w_ih, const float* __restrict__ w_hh,
                       const float* __restrict__ b_ih, const float* __restrict__ b_hh,
                       signed char* __restrict__ hidden, float* __restrict__ state_out)
{
    const int b   = blockIdx.x;
    const int tau = threadIdx.x;

    __shared__ __align__(16) float xb[2][OBSZ];
    __shared__ __align__(16) float hb[HH];
    __shared__ __align__(16) float srz[2*HH];
    __shared__ __align__(16) float sinb[HH];
    __shared__ __align__(16) float shnb[HH];

    float4 wi4[OBSZ/4];
    float4 wh4[HH/4];
    float bi = 0.f, bh = 0.f;
    if (tau < G3) {
        const float4* wip = (const float4*)(w_ih + tau*OBSZ);
        #pragma unroll
        for (int k4 = 0; k4 < OBSZ/4; ++k4) wi4[k4] = wip[k4];
        const float4* whp = (const float4*)(w_hh + tau*HH);
        #pragma unroll
        for (int j4 = 0; j4 < HH/4; ++j4) wh4[j4] = whp[j4];
        bi = b_ih[tau]; bh = b_hh[tau];
    } else {
        const int hl = tau - G3;
        const int k0 = hl*2;
        float2 v = *(const float2*)(x + (size_t)(0*BB + b)*OBSZ + k0);
        xb[0][k0] = v.x; xb[0][k0+1] = v.y;
        float d0 = done[0*BB + b];
        hb[hl] = (1.0f - d0) * h0[b*HH + hl];
    }
    __syncthreads();

    float dnext = 0.f;
    for (int t = 0; t < TT; ++t) {
        const int cur = t & 1, nxt = cur ^ 1;
        if (tau < G3) {
            const float4* hb4 = (const float4*)hb;
            float a0=0.f, a1=0.f, a2=0.f, a3=0.f;
            #pragma unroll
            for (int j4 = 0; j4 < HH/4; ++j4) {
                float4 hv = hb4[j4];
                a0 = fmaf(hv.x, wh4[j4].x, a0);
                a1 = fmaf(hv.y, wh4[j4].y, a1);
                a2 = fmaf(hv.z, wh4[j4].z, a2);
                a3 = fmaf(hv.w, wh4[j4].w, a3);
            }
            float gh = bh + ((a0+a1)+(a2+a3));
            const float4* xb4 = (const float4*)xb[cur];
            float g0=0.f, g1=0.f, g2=0.f, g3=0.f;
            #pragma unroll
            for (int k4 = 0; k4 < OBSZ/4; ++k4) {
                float4 xv = xb4[k4];
                g0 = fmaf(xv.x, wi4[k4].x, g0);
                g1 = fmaf(xv.y, wi4[k4].y, g1);
                g2 = fmaf(xv.z, wi4[k4].z, g2);
                g3 = fmaf(xv.w, wi4[k4].w, g3);
            }
            float gi = bi + ((g0+g1)+(g2+g3));
            if (tau < 2*HH) srz[tau] = gi + gh;
            else { sinb[tau-2*HH] = gi; shnb[tau-2*HH] = gh; }
        } else {
            const int hl = tau - G3;
            if (t+1 < TT) {
                const int k0 = hl*2;
                float2 xr = *(const float2*)(x + (size_t)((t+1)*BB + b)*OBSZ + k0);
                xb[nxt][k0] = xr.x; xb[nxt][k0+1] = xr.y;
                dnext = done[(t+1)*BB + b];
            }
        }
        __syncthreads();

        if (tau >= G3) {
            const int hl = tau - G3;
            float sr = srz[hl];
            float sz = srz[HH + hl];
            float r = 1.0f / (1.0f + expf(-sr));
            float z = 1.0f / (1.0f + expf(-sz));
            float n = tanhf(sinb[hl] + r * shnb[hl]);
            float hm = hb[hl];
            float hnew = (1.0f - z)*n + z*hm;
            float s = (hnew > 0.f) ? 1.f : ((hnew < 0.f) ? -1.f : 0.f);
            hidden[(size_t)(t*BB + b)*HH + hl] = (signed char)s;
            if (t == TT-1) state_out[b*HH + hl] = s;
            hb[hl] = (t+1 < TT && dnext != 0.f) ? 0.f : s;
        }
        __syncthreads();
    }
}

// ---------------------------------------------------------------------------
// MERGED actor+critic 3-layer MLP (r12 verbatim -- proven ~97us).
// ---------------------------------------------------------------------------
__global__ __launch_bounds__(256, 2)
void mlp_both_kernel(const signed char* __restrict__ hidden, const float* __restrict__ x,
                     const float* __restrict__ a_w1, const float* __restrict__ a_b1,
                     const float* __restrict__ a_w2, const float* __restrict__ a_b2,
                     const float* __restrict__ a_w3, const float* __restrict__ a_b3,
                     const float* __restrict__ c_w1, const float* __restrict__ c_b1,
                     const float* __restrict__ c_w2, const float* __restrict__ c_b2,
                     const float* __restrict__ c_w3, const float* __restrict__ c_b3,
                     float* __restrict__ logits, float* __restrict__ value)
{
    const int head = blockIdx.y;                 // 0=actor, 1=critic (uniform)
    const float* w1 = head ? c_w1 : a_w1;
    const float* b1 = head ? c_b1 : a_b1;
    const float* w2 = head ? c_w2 : a_w2;
    const float* b2 = head ? c_b2 : a_b2;
    const float* w3 = head ? c_w3 : a_w3;
    const float* b3 = head ? c_b3 : a_b3;
    const int  nout = head ? 1 : 16;
    float* out      = head ? value : logits;

    __shared__ __align__(16) float wbuf[64*100];
    __shared__ __align__(16) float ybuf[128*68];
    const int tid = threadIdx.x;
    const int g   = tid >> 3;
    const int q   = tid & 7;

    float bv1[8], bv2[8];
    #pragma unroll
    for (int j = 0; j < 8; ++j) { bv1[j] = b1[q + 8*j]; bv2[j] = b2[q + 8*j]; }

    for (int chunk = 0; chunk < 2; ++chunk) {
        const int row0 = blockIdx.x*256 + chunk*128 + g*4;

        float acc[8][4];
        #pragma unroll
        for (int j = 0; j < 8; ++j)
            #pragma unroll
            for (int r = 0; r < 4; ++r) acc[j][r] = bv1[j];

        auto dot8 = [&](float (&cv)[4][8], int colbase) {
            #pragma unroll
            for (int j = 0; j < 8; ++j) {
                const float* wp = &wbuf[(q + 8*j)*100 + colbase];
                float4 w0 = *(const float4*)wp;
                float4 w1v = *(const float4*)(wp + 4);
                #pragma unroll
                for (int r = 0; r < 4; ++r) {
                    acc[j][r] = fmaf(cv[r][0], w0.x,  acc[j][r]);
                    acc[j][r] = fmaf(cv[r][1], w0.y,  acc[j][r]);
                    acc[j][r] = fmaf(cv[r][2], w0.z,  acc[j][r]);
                    acc[j][r] = fmaf(cv[r][3], w0.w,  acc[j][r]);
                    acc[j][r] = fmaf(cv[r][4], w1v.x, acc[j][r]);
                    acc[j][r] = fmaf(cv[r][5], w1v.y, acc[j][r]);
                    acc[j][r] = fmaf(cv[r][6], w1v.z, acc[j][r]);
                    acc[j][r] = fmaf(cv[r][7], w1v.w, acc[j][r]);
                }
            }
        };

        #pragma unroll
        for (int half = 0; half < 2; ++half) {
            __syncthreads();
            #pragma unroll
            for (int i = 0; i < 6; ++i) {
                int v = tid + i*256;
                int f = v / 24, k4 = v % 24;
                *(float4*)&wbuf[f*100 + k4*4] =
                    *(const float4*)&w1[f*G3 + half*96 + k4*4];
            }
            __syncthreads();

            if (half == 0) {
                for (int kc = 0; kc < 8; ++kc) {
                    float cv[4][8];
                    #pragma unroll
                    for (int r = 0; r < 4; ++r) {
                        uint2 hv = *(const uint2*)(hidden + (size_t)(row0+r)*HH + kc*8);
                        cv[r][0] = (float)(signed char)(hv.x);
                        cv[r][1] = (float)(signed char)(hv.x >> 8);
                        cv[r][2] = (float)(signed char)(hv.x >> 16);
                        cv[r][3] = (float)(signed char)(hv.x >> 24);
                        cv[r][4] = (float)(signed char)(hv.y);
                        cv[r][5] = (float)(signed char)(hv.y >> 8);
                        cv[r][6] = (float)(signed char)(hv.y >> 16);
                        cv[r][7] = (float)(signed char)(hv.y >> 24);
                    }
                    dot8(cv, kc*8);
                }
                for (int kc = 0; kc < 4; ++kc) {
                    float cv[4][8];
                    #pragma unroll
                    for (int r = 0; r < 4; ++r) {
                        const float* xp = x + (size_t)(row0+r)*OBSZ + kc*8;
                        float4 a = *(const float4*)xp;
                        float4 c = *(const float4*)(xp + 4);
                        cv[r][0]=a.x; cv[r][1]=a.y; cv[r][2]=a.z; cv[r][3]=a.w;
                        cv[r][4]=c.x; cv[r][5]=c.y; cv[r][6]=c.z; cv[r][7]=c.w;
                    }
                    dot8(cv, 64 + kc*8);
                }
            } else {
                for (int kc = 0; kc < 12; ++kc) {
                    float cv[4][8];
                    #pragma unroll
                    for (int r = 0; r < 4; ++r) {
                        const float* xp = x + (size_t)(row0+r)*OBSZ + 32 + kc*8;
                        float4 a = *(const float4*)xp;
                        float4 c = *(const float4*)(xp + 4);
                        cv[r][0]=a.x; cv[r][1]=a.y; cv[r][2]=a.z; cv[r][3]=a.w;
                        cv[r][4]=c.x; cv[r][5]=c.y; cv[r][6]=c.z; cv[r][7]=c.w;
                    }
                    dot8(cv, kc*8);
                }
            }
        }

        #pragma unroll
        for (int j = 0; j < 8; ++j)
            #pragma unroll
            for (int r = 0; r < 4; ++r)
                ybuf[(g*4+r)*68 + q + 8*j] = tanh_fast(acc[j][r]);
        __syncthreads();

        #pragma unroll
        for (int i = 0; i < 4; ++i) {
            int v = tid + i*256;
            int f = v >> 4, k4 = v & 15;
            *(float4*)&wbuf[f*68 + k4*4] = *(const float4*)&w2[f*HH + k4*4];
        }
        __syncthreads();

        float acc2[8][4];
        #pragma unroll
        for (int j = 0; j < 8; ++j)
            #pragma unroll
            for (int r = 0; r < 4; ++r) acc2[j][r] = bv2[j];

        for (int kc = 0; kc < 8; ++kc) {
            float cv[4][8];
            #pragma unroll
            for (int r = 0; r < 4; ++r) {
                const float* yp = &ybuf[(g*4+r)*68 + kc*8];
                float4 a = *(const float4*)yp;
                float4 c = *(const float4*)(yp + 4);
                cv[r][0]=a.x; cv[r][1]=a.y; cv[r][2]=a.z; cv[r][3]=a.w;
                cv[r][4]=c.x; cv[r][5]=c.y; cv[r][6]=c.z; cv[r][7]=c.w;
            }
            #pragma unroll
            for (int j = 0; j < 8; ++j) {
                const float* wp = &wbuf[(q + 8*j)*68 + kc*8];
                float4 w0 = *(const float4*)wp;
                float4 w1v = *(const float4*)(wp + 4);
                #pragma unroll
                for (int r = 0; r < 4; ++r) {
                    acc2[j][r] = fmaf(cv[r][0], w0.x,  acc2[j][r]);
                    acc2[j][r] = fmaf(cv[r][1], w0.y,  acc2[j][r]);
                    acc2[j][r] = fmaf(cv[r][2], w0.z,  acc2[j][r]);
                    acc2[j][r] = fmaf(cv[r][3], w0.w,  acc2[j][r]);
                    acc2[j][r] = fmaf(cv[r][4], w1v.x, acc2[j][r]);
                    acc2[j][r] = fmaf(cv[r][5], w1v.y, acc2[j][r]);
                    acc2[j][r] = fmaf(cv[r][6], w1v.z, acc2[j][r]);
                    acc2[j][r] = fmaf(cv[r][7], w1v.w, acc2[j][r]);
                }
            }
        }
        __syncthreads();   // all y1 reads done before overwrite

        #pragma unroll
        for (int j = 0; j < 8; ++j)
            #pragma unroll
            for (int r = 0; r < 4; ++r)
                ybuf[(g*4+r)*68 + q + 8*j] = tanh_fast(acc2[j][r]);
        if (tid < nout*16) {                       // stage w3 [nout][64]->stride 68
            int f = tid >> 4, k4 = tid & 15;
            *(float4*)&wbuf[f*68 + k4*4] = *(const float4*)&w3[f*HH + k4*4];
        }
        __syncthreads();

        for (int oo = 0; oo < (nout + 7)/8; ++oo) {
            const int o = q + 8*oo;
            if (o < nout) {
                #pragma unroll
                for (int r = 0; r < 4; ++r) {
                    const float* yp = &ybuf[(g*4+r)*68];
                    const float* wp = &wbuf[o*68];
                    float s0=0.f, s1=0.f, s2=0.f, s3=0.f;
                    #pragma unroll
                    for (int k4 = 0; k4 < 16; ++k4) {
                        float4 yv = *(const float4*)(yp + k4*4);
                        float4 wv = *(const float4*)(wp + k4*4);
                        s0 = fmaf(yv.x, wv.x, s0);
                        s1 = fmaf(yv.y, wv.y, s1);
                        s2 = fmaf(yv.z, wv.z, s2);
                        s3 = fmaf(yv.w, wv.w, s3);
                    }
                    out[(size_t)(row0+r)*nout + o] = b3[o] + ((s0+s1)+(s2+s3));
                }
            }
        }
        __syncthreads();   // layer3 ybuf/wbuf reads done before next chunk
    }
}

extern "C" void kernel_launch(void* const* d_in, const int* in_sizes, int n_in,
                              void* d_out, int out_size, void* d_ws, size_t ws_size,
                              hipStream_t stream) {
    const float* x     = (const float*)d_in[0];
    const float* h0    = (const float*)d_in[1];
    const float* done  = (const float*)d_in[2];
    const float* w_ih  = (const float*)d_in[3];
    const float* w_hh  = (const float*)d_in[4];
    const float* b_ih  = (const float*)d_in[5];
    const float* b_hh  = (const float*)d_in[6];
    const float* a_w1  = (const float*)d_in[7];
    const float* a_b1  = (const float*)d_in[8];
    const float* a_w2  = (const float*)d_in[9];
    const float* a_b2  = (const float*)d_in[10];
    const float* a_w3  = (const float*)d_in[11];
    const float* a_b3  = (const float*)d_in[12];
    const float* c_w1  = (const float*)d_in[13];
    const float* c_b1  = (const float*)d_in[14];
    const float* c_w2  = (const float*)d_in[15];
    const float* c_b2  = (const float*)d_in[16];
    const float* c_w3  = (const float*)d_in[17];
    const float* c_b3  = (const float*)d_in[18];

    float* out    = (float*)d_out;
    float* logits = out;                       // [131072, 16]
    float* value  = out + (size_t)NROW*16;     // [131072]
    float* state  = value + NROW;              // [1, 256, 64]

    // workspace layout: [segs 128KB][segcnt 1KB][hidden 8.39MB][gi 100.66MB]
    const size_t segs_bytes   = (size_t)BB * SEGCAP * sizeof(unsigned int);
    const size_t segcnt_bytes = (size_t)BB * sizeof(int);
    const size_t hidden_off   = segs_bytes + segcnt_bytes;
    const size_t hidden_bytes = (size_t)NROW * HH;
    const size_t gi_off       = hidden_off + hidden_bytes;
    const size_t gi_bytes     = (size_t)NROW * G3 * sizeof(float);

    if (ws_size >= gi_off + gi_bytes) {
        unsigned int* segs = (unsigned int*)d_ws;
        int* segcnt        = (int*)((char*)d_ws + segs_bytes);
        signed char* hidden = (signed char*)((char*)d_ws + hidden_off);
        float* gi_ws       = (float*)((char*)d_ws + gi_off);

        seg_build_kernel<<<BB, 64, 0, stream>>>(done, segs, segcnt);
        gi_proj_kernel<<<dim3(NROW/32, 2), 256, 0, stream>>>(x, w_ih, b_ih, gi_ws);
        seg_scan_kernel<<<dim3(BB, SEGCAP/2), 512, 0, stream>>>(
            gi_ws, h0, done, w_hh, b_hh, segs, segcnt, hidden, state);
        mlp_both_kernel<<<dim3(512, 2), 256, 0, stream>>>(
            hidden, x, a_w1, a_b1, a_w2, a_b2, a_w3, a_b3,
            c_w1, c_b1, c_w2, c_b2, c_w3, c_b3, logits, value);
    } else {
        signed char* hidden = (signed char*)d_ws;
        scan_kernel_fused<<<BB, 256, 0, stream>>>(x, h0, done, w_ih, w_hh,
                                                  b_ih, b_hh, hidden, state);
        mlp_both_kernel<<<dim3(512, 2), 256, 0, stream>>>(
            hidden, x, a_w1, a_b1, a_w2, a_b2, a_w3, a_b3,
            c_w1, c_b1, c_w2, c_b2, c_w3, c_b3, logits, value);
    }
}

// Round 18
// 470.939 us; speedup vs baseline: 1.0806x; 1.0806x over previous
//
#include <hip/hip_runtime.h>
#include <math.h>

#define TT 512
#define BB 256
#define OBSZ 128
#define HH 64
#define G3 192
#define NROW (TT*BB)
#define SEGCAP 128

// ---- fast transcendentals: ONLY used downstream of sign() (MLP heads) -----
__device__ __forceinline__ float fast_rcp(float x) {
    return __builtin_amdgcn_rcpf(x);
}
__device__ __forceinline__ float tanh_fast(float x) {
    float xc = fminf(fmaxf(x, -20.0f), 20.0f);   // clamp: avoid inf/inf NaN
    float e2 = __expf(2.0f * xc);
    return (e2 - 1.0f) * fast_rcp(e2 + 1.0f);
}

// ---------------------------------------------------------------------------
// Segment table build + length-desc sort (r7/r8 verbatim).
// ---------------------------------------------------------------------------
__global__ __launch_bounds__(64, 1)
void seg_build_kernel(const float* __restrict__ done,
                      unsigned int* __restrict__ segs, int* __restrict__ segcnt)
{
    const int b = blockIdx.x;
    const int l = threadIdx.x;
    __shared__ int starts[SEGCAP];
    __shared__ int scnt_s;

    unsigned int m = 0;
    #pragma unroll
    for (int k = 0; k < 8; ++k) {
        int t = l*8 + k;
        float d = done[(size_t)t*BB + b];
        if (t > 0 && d != 0.f) m |= (1u << k);
    }
    int cnt = __popc(m) + (l == 0 ? 1 : 0);
    int inc = cnt;
    for (int s = 1; s < 64; s <<= 1) {
        int v = __shfl_up(inc, s);
        if (l >= s) inc += v;
    }
    int total = __shfl(inc, 63);
    int w = inc - cnt;
    if (l == 0 && w < SEGCAP) starts[w++] = 0;
    #pragma unroll
    for (int k = 0; k < 8; ++k)
        if (m & (1u << k)) { if (w < SEGCAP) starts[w] = l*8 + k; ++w; }
    if (l == 0) scnt_s = (total < SEGCAP) ? total : SEGCAP;
    __syncthreads();

    const int n = scnt_s;
    for (int i = l; i < n; i += 64) {
        int t0 = starts[i];
        int t1 = (i+1 < n) ? starts[i+1] : TT;
        int li = t1 - t0;
        int rank = 0;
        for (int j = 0; j < n; ++j) {
            int s0 = starts[j];
            int s1 = (j+1 < n) ? starts[j+1] : TT;
            int lj = s1 - s0;
            rank += (int)((lj > li) || (lj == li && j < i));
        }
        segs[(size_t)b*SEGCAP + rank] = (unsigned int)t0 | ((unsigned int)li << 16);
    }
    if (l == 0) segcnt[b] = n;
}

// ---------------------------------------------------------------------------
// Segment-parallel GRU scan v5 (proven 228us, r10-r16 -- structural floor:
// transpose null, w-shared quad -24%, occupancy pairing +5% kept).
// ---------------------------------------------------------------------------
__global__ __launch_bounds__(512, 6)
void seg_scan_kernel(const float* __restrict__ gi_ws, const float* __restrict__ h0,
                     const float* __restrict__ done,
                     const float* __restrict__ w_hh, const float* __restrict__ b_hh,
                     const unsigned int* __restrict__ segs, const int* __restrict__ segcnt,
                     signed char* __restrict__ hidden, float* __restrict__ state_out)
{
    const int b    = blockIdx.x;
    const int scnt = segcnt[b];
    const int si0  = blockIdx.y * 2;
    if (si0 >= scnt) return;                     // uniform: both pair slots empty

    __shared__ __align__(16) float ws[G3*68];    // 52.2 KB
    __shared__ __align__(16) float hb[2][HH];
    __shared__ __align__(16) float srz[2][2*HH];
    __shared__ __align__(16) float shnb[2][HH];  // total 54,272 B -> 3 blocks/CU

    const int tid = threadIdx.x;
    #pragma unroll
    for (int i = 0; i < 6; ++i) {                // stage w_hh [192][64] -> stride 68
        int idx = tid + i*512;                   // float4 chunk 0..3071
        int g = idx >> 4, k4 = idx & 15;
        *(float4*)&ws[g*68 + k4*4] = *(const float4*)&w_hh[g*HH + k4*4];
    }

    const int grp = tid >> 8;                    // segment group 0/1 (wave-aligned)
    const int tau = tid & 255;                   // thread index within group
    const int si  = si0 + grp;

    int t0 = 0, len = 0;
    if (si < scnt) {
        unsigned int sg = segs[(size_t)b*SEGCAP + si];
        t0  = (int)(sg & 0xffffu);
        len = (int)(sg >> 16);
    }
    // uniform loop bound: sorted order -> rank si0 is the longer of the pair
    const int lmax = (int)(segs[(size_t)b*SEGCAP + si0] >> 16);

    const size_t gbase = (size_t)b*TT;           // [b][t][G3] layout

    float bh = 0.f, gp0 = 0.f, gp1 = 0.f;        // dot threads (r,z,n rows)
    float gn0 = 0.f, gn1 = 0.f;                  // gate threads: own gi_n stream
    if (tau < G3) {
        bh  = b_hh[tau];
        gp0 = gi_ws[(gbase + t0)*G3 + tau];
        if (len > 1) gp1 = gi_ws[(gbase + t0+1)*G3 + tau];
    } else {
        const int hl = tau - G3;
        float hi = 0.f;
        if (len > 0 && t0 == 0) {
            float d0 = done[b];
            hi = (1.0f - d0) * h0[b*HH + hl];
        }
        hb[grp][hl] = hi;
        gn0 = gi_ws[(gbase + t0)*G3 + 128 + hl];
        if (len > 1) gn1 = gi_ws[(gbase + t0+1)*G3 + 128 + hl];
    }
    __syncthreads();

    for (int tt = 0; tt < lmax; ++tt) {
        const int t = t0 + tt;
        if (tau < G3 && tt < len) {
            float gi = gp0;
            gp0 = gp1;
            if (tt+2 < len) gp1 = gi_ws[(gbase + t+2)*G3 + tau];
            // h via one lane-spread b32 read + readlane (bit-copy -> exact)
            int hvi = __float_as_int(hb[grp][tau & 63]);
            const float* wrow = &ws[tau*68];
            float a0=0.f, a1=0.f, a2=0.f, a3=0.f;
            #pragma unroll
            for (int j4 = 0; j4 < HH/4; ++j4) {
                float4 wv = *(const float4*)(wrow + j4*4);
                a0 = fmaf(__int_as_float(__builtin_amdgcn_readlane(hvi, 4*j4+0)), wv.x, a0);
                a1 = fmaf(__int_as_float(__builtin_amdgcn_readlane(hvi, 4*j4+1)), wv.y, a1);
                a2 = fmaf(__int_as_float(__builtin_amdgcn_readlane(hvi, 4*j4+2)), wv.z, a2);
                a3 = fmaf(__int_as_float(__builtin_amdgcn_readlane(hvi, 4*j4+3)), wv.w, a3);
            }
            float gh = bh + ((a0+a1)+(a2+a3));
            if (tau < 2*HH) srz[grp][tau] = gi + gh;        // r,z pre-acts
            else            shnb[grp][tau-2*HH] = gh;       // n: gh only
        }
        __syncthreads();   // (A) srz/shnb ready; hb reads complete

        if (tau >= G3 && tt < len) {
            const int hl = tau - G3;
            float gin = gn0;
            gn0 = gn1;
            if (tt+2 < len) gn1 = gi_ws[(gbase + t+2)*G3 + 128 + hl];
            float sr = srz[grp][hl];
            float sz = srz[grp][HH + hl];
            float r = 1.0f / (1.0f + expf(-sr));   // libm: precision-critical
            float z = 1.0f / (1.0f + expf(-sz));
            float n = tanhf(gin + r * shnb[grp][hl]);
            float hm = hb[grp][hl];
            float hnew = (1.0f - z)*n + z*hm;
            float s = (hnew > 0.f) ? 1.f : ((hnew < 0.f) ? -1.f : 0.f);
            hidden[(size_t)(t*BB + b)*HH + hl] = (signed char)s;
            if (t == TT-1) state_out[b*HH + hl] = s;
            hb[grp][hl] = s;   // interior steps of a segment have done==0
        }
        __syncthreads();   // (B) hb ready for next step
    }
}

// ---------------------------------------------------------------------------
// gi projection (r14/r16 proven: (6g,4r), 2 blocks/CU, single g-range,
// output permuted to [b][t][G3]). r17's g-split regressed (x-latency-bound,
// not wave-starved). Chains: k mod 4 -> c0..c3, k ascending (half0 then
// half1), final b + ((c0+c1)+(c2+c3)) -> BIT-IDENTICAL to all passing rounds.
// ---------------------------------------------------------------------------
__global__ __launch_bounds__(256, 2)
void gi_proj_kernel(const float* __restrict__ x,
                    const float* __restrict__ w_ih, const float* __restrict__ b_ih,
                    float* __restrict__ gi_ws)
{
    __shared__ __align__(16) float ws[G3*68];     // 52.2 KB
    const int tid  = threadIdx.x;
    const int q    = tid & 31;    // g-lane: owns g = q + 32*jj, jj=0..5
    const int rp   = tid >> 5;    // row-group 0..7: rows rp*4 .. rp*4+3
    const int rowb = blockIdx.x * 32;

    float bg[6];
    #pragma unroll
    for (int jj = 0; jj < 6; ++jj) bg[jj] = b_ih[q + 32*jj];

    float c0[6][4], c1[6][4], c2[6][4], c3[6][4];
    #pragma unroll
    for (int jj = 0; jj < 6; ++jj)
        #pragma unroll
        for (int r = 0; r < 4; ++r) { c0[jj][r]=0.f; c1[jj][r]=0.f; c2[jj][r]=0.f; c3[jj][r]=0.f; }

    #pragma unroll
    for (int half = 0; half < 2; ++half) {
        __syncthreads();                         // prior-half readers done
        #pragma unroll
        for (int i = 0; i < 12; ++i) {           // stage w half [192][64] -> stride 68
            int idx = tid + i*256;               // 0..3071
            int g = idx >> 4, k4 = idx & 15;
            *(float4*)&ws[g*68 + k4*4] =
                *(const float4*)&w_ih[(size_t)g*OBSZ + half*64 + k4*4];
        }
        __syncthreads();

        for (int kc = 0; kc < 8; ++kc) {         // 8 k-floats per chunk
            float cv[4][8];
            #pragma unroll
            for (int r = 0; r < 4; ++r) {
                const float* xp = x + (size_t)(rowb + rp*4 + r)*OBSZ + half*64 + kc*8;
                float4 a = *(const float4*)xp;
                float4 c = *(const float4*)(xp + 4);
                cv[r][0]=a.x; cv[r][1]=a.y; cv[r][2]=a.z; cv[r][3]=a.w;
                cv[r][4]=c.x; cv[r][5]=c.y; cv[r][6]=c.z; cv[r][7]=c.w;
            }
            #pragma unroll
            for (int jj = 0; jj < 6; ++jj) {
                const float* wp = &ws[(q + 32*jj)*68 + kc*8];
                float4 w0 = *(const float4*)wp;
                float4 w1 = *(const float4*)(wp + 4);
                #pragma unroll
                for (int r = 0; r < 4; ++r) {
                    c0[jj][r] = fmaf(cv[r][0], w0.x, c0[jj][r]);
                    c1[jj][r] = fmaf(cv[r][1], w0.y, c1[jj][r]);
                    c2[jj][r] = fmaf(cv[r][2], w0.z, c2[jj][r]);
                    c3[jj][r] = fmaf(cv[r][3], w0.w, c3[jj][r]);
                    c0[jj][r] = fmaf(cv[r][4], w1.x, c0[jj][r]);
                    c1[jj][r] = fmaf(cv[r][5], w1.y, c1[jj][r]);
                    c2[jj][r] = fmaf(cv[r][6], w1.z, c2[jj][r]);
                    c3[jj][r] = fmaf(cv[r][7], w1.w, c3[jj][r]);
                }
            }
        }
    }

    #pragma unroll
    for (int r = 0; r < 4; ++r) {
        const int row = rowb + rp*4 + r;                 // = t*BB + b
        const size_t rowp = ((size_t)(row & (BB-1)) << 9) | (row >> 8);  // b*TT+t
        #pragma unroll
        for (int jj = 0; jj < 6; ++jj) {
            float o = bg[jj] + ((c0[jj][r]+c1[jj][r]) + (c2[jj][r]+c3[jj][r]));
            gi_ws[rowp*G3 + q + 32*jj] = o;
        }
    }
}

// ---------------------------------------------------------------------------
// Fallback fused scan (round-4 verbatim) for when ws_size is too small.
// ---------------------------------------------------------------------------
__global__ __launch_bounds__(256, 1)
void scan_kernel_fused(const float* __restrict__ x, const float* __restrict__ h0,
                       const float* __restrict__ done,
                       const float* __restrict__ w_ih, const float* __restrict__ w_hh,
                       const float* __restrict__ b_ih, const float* __restrict__ b_hh,
                       signed char* __restrict__ hidden, float* __restrict__ state_out)
{
    const int b   = blockIdx.x;
    const int tau = threadIdx.x;

    __shared__ __align__(16) float xb[2][OBSZ];
    __shared__ __align__(16) float hb[HH];
    __shared__ __align__(16) float srz[2*HH];
    __shared__ __align__(16) float sinb[HH];
    __shared__ __align__(16) float shnb[HH];

    float4 wi4[OBSZ/4];
    float4 wh4[HH/4];
    float bi = 0.f, bh = 0.f;
    if (tau < G3) {
        const float4* wip = (const float4*)(w_ih + tau*OBSZ);
        #pragma unroll
        for (int k4 = 0; k4 < OBSZ/4; ++k4) wi4[k4] = wip[k4];
        const float4* whp = (const float4*)(w_hh + tau*HH);
        #pragma unroll
        for (int j4 = 0; j4 < HH/4; ++j4) wh4[j4] = whp[j4];
        bi = b_ih[tau]; bh = b_hh[tau];
    } else {
        const int hl = tau - G3;
        const int k0 = hl*2;
        float2 v = *(const float2*)(x + (size_t)(0*BB + b)*OBSZ + k0);
        xb[0][k0] = v.x; xb[0][k0+1] = v.y;
        float d0 = done[0*BB + b];
        hb[hl] = (1.0f - d0) * h0[b*HH + hl];
    }
    __syncthreads();

    float dnext = 0.f;
    for (int t = 0; t < TT; ++t) {
        const int cur = t & 1, nxt = cur ^ 1;
        if (tau < G3) {
            const float4* hb4 = (const float4*)hb;
            float a0=0.f, a1=0.f, a2=0.f, a3=0.f;
            #pragma unroll
            for (int j4 = 0; j4 < HH/4; ++j4) {
                float4 hv = hb4[j4];
                a0 = fmaf(hv.x, wh4[j4].x, a0);
                a1 = fmaf(hv.y, wh4[j4].y, a1);
                a2 = fmaf(hv.z, wh4[j4].z, a2);
                a3 = fmaf(hv.w, wh4[j4].w, a3);
            }
            float gh = bh + ((a0+a1)+(a2+a3));
            const float4* xb4 = (const float4*)xb[cur];
            float g0=0.f, g1=0.f, g2=0.f, g3=0.f;
            #pragma unroll
            for (int k4 = 0; k4 < OBSZ/4; ++k4) {
                float4 xv = xb4[k4];
                g0 = fmaf(xv.x, wi4[k4].x, g0);
                g1 = fmaf(xv.y, wi4[k4].y, g1);
                g2 = fmaf(xv.z, wi4[k4].z, g2);
                g3 = fmaf(xv.w, wi4[k4].w, g3);
            }
            float gi = bi + ((g0+g1)+(g2+g3));
            if (tau < 2*HH) srz[tau] = gi + gh;
            else { sinb[tau-2*HH] = gi; shnb[tau-2*HH] = gh; }
        } else {
            const int hl = tau - G3;
            if (t+1 < TT) {
                const int k0 = hl*2;
                float2 xr = *(const float2*)(x + (size_t)((t+1)*BB + b)*OBSZ + k0);
                xb[nxt][k0] = xr.x; xb[nxt][k0+1] = xr.y;
                dnext = done[(t+1)*BB + b];
            }
        }
        __syncthreads();

        if (tau >= G3) {
            const int hl = tau - G3;
            float sr = srz[hl];
            float sz = srz[HH + hl];
            float r = 1.0f / (1.0f + expf(-sr));
            float z = 1.0f / (1.0f + expf(-sz));
            float n = tanhf(sinb[hl] + r * shnb[hl]);
            float hm = hb[hl];
            float hnew = (1.0f - z)*n + z*hm;
            float s = (hnew > 0.f) ? 1.f : ((hnew < 0.f) ? -1.f : 0.f);
            hidden[(size_t)(t*BB + b)*HH + hl] = (signed char)s;
            if (t == TT-1) state_out[b*HH + hl] = s;
            hb[hl] = (t+1 < TT && dnext != 0.f) ? 0.f : s;
        }
        __syncthreads();
    }
}

// ---------------------------------------------------------------------------
// MERGED actor+critic 3-layer MLP (r12 verbatim -- proven ~97us).
// ---------------------------------------------------------------------------
__global__ __launch_bounds__(256, 2)
void mlp_both_kernel(const signed char* __restrict__ hidden, const float* __restrict__ x,
                     const float* __restrict__ a_w1, const float* __restrict__ a_b1,
                     const float* __restrict__ a_w2, const float* __restrict__ a_b2,
                     const float* __restrict__ a_w3, const float* __restrict__ a_b3,
                     const float* __restrict__ c_w1, const float* __restrict__ c_b1,
                     const float* __restrict__ c_w2, const float* __restrict__ c_b2,
                     const float* __restrict__ c_w3, const float* __restrict__ c_b3,
                     float* __restrict__ logits, float* __restrict__ value)
{
    const int head = blockIdx.y;                 // 0=actor, 1=critic (uniform)
    const float* w1 = head ? c_w1 : a_w1;
    const float* b1 = head ? c_b1 : a_b1;
    const float* w2 = head ? c_w2 : a_w2;
    const float* b2 = head ? c_b2 : a_b2;
    const float* w3 = head ? c_w3 : a_w3;
    const float* b3 = head ? c_b3 : a_b3;
    const int  nout = head ? 1 : 16;
    float* out      = head ? value : logits;

    __shared__ __align__(16) float wbuf[64*100];
    __shared__ __align__(16) float ybuf[128*68];
    const int tid = threadIdx.x;
    const int g   = tid >> 3;
    const int q   = tid & 7;

    float bv1[8], bv2[8];
    #pragma unroll
    for (int j = 0; j < 8; ++j) { bv1[j] = b1[q + 8*j]; bv2[j] = b2[q + 8*j]; }

    for (int chunk = 0; chunk < 2; ++chunk) {
        const int row0 = blockIdx.x*256 + chunk*128 + g*4;

        float acc[8][4];
        #pragma unroll
        for (int j = 0; j < 8; ++j)
            #pragma unroll
            for (int r = 0; r < 4; ++r) acc[j][r] = bv1[j];

        auto dot8 = [&](float (&cv)[4][8], int colbase) {
            #pragma unroll
            for (int j = 0; j < 8; ++j) {
                const float* wp = &wbuf[(q + 8*j)*100 + colbase];
                float4 w0 = *(const float4*)wp;
                float4 w1v = *(const float4*)(wp + 4);
                #pragma unroll
                for (int r = 0; r < 4; ++r) {
                    acc[j][r] = fmaf(cv[r][0], w0.x,  acc[j][r]);
                    acc[j][r] = fmaf(cv[r][1], w0.y,  acc[j][r]);
                    acc[j][r] = fmaf(cv[r][2], w0.z,  acc[j][r]);
                    acc[j][r] = fmaf(cv[r][3], w0.w,  acc[j][r]);
                    acc[j][r] = fmaf(cv[r][4], w1v.x, acc[j][r]);
                    acc[j][r] = fmaf(cv[r][5], w1v.y, acc[j][r]);
                    acc[j][r] = fmaf(cv[r][6], w1v.z, acc[j][r]);
                    acc[j][r] = fmaf(cv[r][7], w1v.w, acc[j][r]);
                }
            }
        };

        #pragma unroll
        for (int half = 0; half < 2; ++half) {
            __syncthreads();
            #pragma unroll
            for (int i = 0; i < 6; ++i) {
                int v = tid + i*256;
                int f = v / 24, k4 = v % 24;
                *(float4*)&wbuf[f*100 + k4*4] =
                    *(const float4*)&w1[f*G3 + half*96 + k4*4];
            }
            __syncthreads();

            if (half == 0) {
                for (int kc = 0; kc < 8; ++kc) {
                    float cv[4][8];
                    #pragma unroll
                    for (int r = 0; r < 4; ++r) {
                        uint2 hv = *(const uint2*)(hidden + (size_t)(row0+r)*HH + kc*8);
                        cv[r][0] = (float)(signed char)(hv.x);
                        cv[r][1] = (float)(signed char)(hv.x >> 8);
                        cv[r][2] = (float)(signed char)(hv.x >> 16);
                        cv[r][3] = (float)(signed char)(hv.x >> 24);
                        cv[r][4] = (float)(signed char)(hv.y);
                        cv[r][5] = (float)(signed char)(hv.y >> 8);
                        cv[r][6] = (float)(signed char)(hv.y >> 16);
                        cv[r][7] = (float)(signed char)(hv.y >> 24);
                    }
                    dot8(cv, kc*8);
                }
                for (int kc = 0; kc < 4; ++kc) {
                    float cv[4][8];
                    #pragma unroll
                    for (int r = 0; r < 4; ++r) {
                        const float* xp = x + (size_t)(row0+r)*OBSZ + kc*8;
                        float4 a = *(const float4*)xp;
                        float4 c = *(const float4*)(xp + 4);
                        cv[r][0]=a.x; cv[r][1]=a.y; cv[r][2]=a.z; cv[r][3]=a.w;
                        cv[r][4]=c.x; cv[r][5]=c.y; cv[r][6]=c.z; cv[r][7]=c.w;
                    }
                    dot8(cv, 64 + kc*8);
                }
            } else {
                for (int kc = 0; kc < 12; ++kc) {
                    float cv[4][8];
                    #pragma unroll
                    for (int r = 0; r < 4; ++r) {
                        const float* xp = x + (size_t)(row0+r)*OBSZ + 32 + kc*8;
                        float4 a = *(const float4*)xp;
                        float4 c = *(const float4*)(xp + 4);
                        cv[r][0]=a.x; cv[r][1]=a.y; cv[r][2]=a.z; cv[r][3]=a.w;
                        cv[r][4]=c.x; cv[r][5]=c.y; cv[r][6]=c.z; cv[r][7]=c.w;
                    }
                    dot8(cv, kc*8);
                }
            }
        }

        #pragma unroll
        for (int j = 0; j < 8; ++j)
            #pragma unroll
            for (int r = 0; r < 4; ++r)
                ybuf[(g*4+r)*68 + q + 8*j] = tanh_fast(acc[j][r]);
        __syncthreads();

        #pragma unroll
        for (int i = 0; i < 4; ++i) {
            int v = tid + i*256;
            int f = v >> 4, k4 = v & 15;
            *(float4*)&wbuf[f*68 + k4*4] = *(const float4*)&w2[f*HH + k4*4];
        }
        __syncthreads();

        float acc2[8][4];
        #pragma unroll
        for (int j = 0; j < 8; ++j)
            #pragma unroll
            for (int r = 0; r < 4; ++r) acc2[j][r] = bv2[j];

        for (int kc = 0; kc < 8; ++kc) {
            float cv[4][8];
            #pragma unroll
            for (int r = 0; r < 4; ++r) {
                const float* yp = &ybuf[(g*4+r)*68 + kc*8];
                float4 a = *(const float4*)yp;
                float4 c = *(const float4*)(yp + 4);
                cv[r][0]=a.x; cv[r][1]=a.y; cv[r][2]=a.z; cv[r][3]=a.w;
                cv[r][4]=c.x; cv[r][5]=c.y; cv[r][6]=c.z; cv[r][7]=c.w;
            }
            #pragma unroll
            for (int j = 0; j < 8; ++j) {
                const float* wp = &wbuf[(q + 8*j)*68 + kc*8];
                float4 w0 = *(const float4*)wp;
                float4 w1v = *(const float4*)(wp + 4);
                #pragma unroll
                for (int r = 0; r < 4; ++r) {
                    acc2[j][r] = fmaf(cv[r][0], w0.x,  acc2[j][r]);
                    acc2[j][r] = fmaf(cv[r][1], w0.y,  acc2[j][r]);
                    acc2[j][r] = fmaf(cv[r][2], w0.z,  acc2[j][r]);
                    acc2[j][r] = fmaf(cv[r][3], w0.w,  acc2[j][r]);
                    acc2[j][r] = fmaf(cv[r][4], w1v.x, acc2[j][r]);
                    acc2[j][r] = fmaf(cv[r][5], w1v.y, acc2[j][r]);
                    acc2[j][r] = fmaf(cv[r][6], w1v.z, acc2[j][r]);
                    acc2[j][r] = fmaf(cv[r][7], w1v.w, acc2[j][r]);
                }
            }
        }
        __syncthreads();   // all y1 reads done before overwrite

        #pragma unroll
        for (int j = 0; j < 8; ++j)
            #pragma unroll
            for (int r = 0; r < 4; ++r)
                ybuf[(g*4+r)*68 + q + 8*j] = tanh_fast(acc2[j][r]);
        if (tid < nout*16) {                       // stage w3 [nout][64]->stride 68
            int f = tid >> 4, k4 = tid & 15;
            *(float4*)&wbuf[f*68 + k4*4] = *(const float4*)&w3[f*HH + k4*4];
        }
        __syncthreads();

        for (int oo = 0; oo < (nout + 7)/8; ++oo) {
            const int o = q + 8*oo;
            if (o < nout) {
                #pragma unroll
                for (int r = 0; r < 4; ++r) {
                    const float* yp = &ybuf[(g*4+r)*68];
                    const float* wp = &wbuf[o*68];
                    float s0=0.f, s1=0.f, s2=0.f, s3=0.f;
                    #pragma unroll
                    for (int k4 = 0; k4 < 16; ++k4) {
                        float4 yv = *(const float4*)(yp + k4*4);
                        float4 wv = *(const float4*)(wp + k4*4);
                        s0 = fmaf(yv.x, wv.x, s0);
                        s1 = fmaf(yv.y, wv.y, s1);
                        s2 = fmaf(yv.z, wv.z, s2);
                        s3 = fmaf(yv.w, wv.w, s3);
                    }
                    out[(size_t)(row0+r)*nout + o] = b3[o] + ((s0+s1)+(s2+s3));
                }
            }
        }
        __syncthreads();   // layer3 ybuf/wbuf reads done before next chunk
    }
}

extern "C" void kernel_launch(void* const* d_in, const int* in_sizes, int n_in,
                              void* d_out, int out_size, void* d_ws, size_t ws_size,
                              hipStream_t stream) {
    const float* x     = (const float*)d_in[0];
    const float* h0    = (const float*)d_in[1];
    const float* done  = (const float*)d_in[2];
    const float* w_ih  = (const float*)d_in[3];
    const float* w_hh  = (const float*)d_in[4];
    const float* b_ih  = (const float*)d_in[5];
    const float* b_hh  = (const float*)d_in[6];
    const float* a_w1  = (const float*)d_in[7];
    const float* a_b1  = (const float*)d_in[8];
    const float* a_w2  = (const float*)d_in[9];
    const float* a_b2  = (const float*)d_in[10];
    const float* a_w3  = (const float*)d_in[11];
    const float* a_b3  = (const float*)d_in[12];
    const float* c_w1  = (const float*)d_in[13];
    const float* c_b1  = (const float*)d_in[14];
    const float* c_w2  = (const float*)d_in[15];
    const float* c_b2  = (const float*)d_in[16];
    const float* c_w3  = (const float*)d_in[17];
    const float* c_b3  = (const float*)d_in[18];

    float* out    = (float*)d_out;
    float* logits = out;                       // [131072, 16]
    float* value  = out + (size_t)NROW*16;     // [131072]
    float* state  = value + NROW;              // [1, 256, 64]

    // workspace layout: [segs 128KB][segcnt 1KB][hidden 8.39MB][gi 100.66MB]
    const size_t segs_bytes   = (size_t)BB * SEGCAP * sizeof(unsigned int);
    const size_t segcnt_bytes = (size_t)BB * sizeof(int);
    const size_t hidden_off   = segs_bytes + segcnt_bytes;
    const size_t hidden_bytes = (size_t)NROW * HH;
    const size_t gi_off       = hidden_off + hidden_bytes;
    const size_t gi_bytes     = (size_t)NROW * G3 * sizeof(float);

    if (ws_size >= gi_off + gi_bytes) {
        unsigned int* segs = (unsigned int*)d_ws;
        int* segcnt        = (int*)((char*)d_ws + segs_bytes);
        signed char* hidden = (signed char*)((char*)d_ws + hidden_off);
        float* gi_ws       = (float*)((char*)d_ws + gi_off);

        seg_build_kernel<<<BB, 64, 0, stream>>>(done, segs, segcnt);
        gi_proj_kernel<<<NROW/32, 256, 0, stream>>>(x, w_ih, b_ih, gi_ws);
        seg_scan_kernel<<<dim3(BB, SEGCAP/2), 512, 0, stream>>>(
            gi_ws, h0, done, w_hh, b_hh, segs, segcnt, hidden, state);
        mlp_both_kernel<<<dim3(512, 2), 256, 0, stream>>>(
            hidden, x, a_w1, a_b1, a_w2, a_b2, a_w3, a_b3,
            c_w1, c_b1, c_w2, c_b2, c_w3, c_b3, logits, value);
    } else {
        signed char* hidden = (signed char*)d_ws;
        scan_kernel_fused<<<BB, 256, 0, stream>>>(x, h0, done, w_ih, w_hh,
                                                  b_ih, b_hh, hidden, state);
        mlp_both_kernel<<<dim3(512, 2), 256, 0, stream>>>(
            hidden, x, a_w1, a_b1, a_w2, a_b2, a_w3, a_b3,
            c_w1, c_b1, c_w2, c_b2, c_w3, c_b3, logits, value);
    }
}